// Round 10
// baseline (746.212 us; speedup 1.0000x reference)
//
#include <hip/hip_runtime.h>
#include <hip/hip_bf16.h>
#include <stdint.h>

// Problem constants: [T,B,D]=[4096,4,1024], H=4096. f32 inputs, f32 outputs.
// Outputs: soft [B,T] f32 at out[0..16384), hard [B,T] f32 at out[16384..32768).
#define T_STEPS 4096
#define BATCH   4
#define D_IN    1024
#define H_DIM   4096
#define M_ROWS  (T_STEPS * BATCH)

typedef __attribute__((ext_vector_type(8))) short bf16x8;
typedef __attribute__((ext_vector_type(4))) float f32x4;

__device__ __forceinline__ float b2f(unsigned short u) {
    union { unsigned int i; float f; } x; x.i = ((unsigned int)u) << 16; return x.f;
}
__device__ __forceinline__ unsigned short f2bf_rne(float f) {
    union { float f; unsigned int u; } v; v.f = f;
    return (unsigned short)((v.u + 0x7FFFu + ((v.u >> 16) & 1u)) >> 16);
}

__device__ __forceinline__ void load_lds16(const unsigned short* g, unsigned short* l) {
    __builtin_amdgcn_global_load_lds(
        (const __attribute__((address_space(1))) void*)g,
        (__attribute__((address_space(3))) void*)l, 16, 0, 0);
}

// ---------------- prep: split X (fat blocks) + transpose W hi-only + zero logits ----------------
// blocks [0,4096): split_x (4 float4/thread) | [4096,6144): W transpose (hi) | [6144,6176): zero
__global__ void __launch_bounds__(256)
prep(const float* __restrict__ hidden,
     const float* __restrict__ Wb1, const float* __restrict__ Wr1,
     unsigned short* __restrict__ Xhi, unsigned short* __restrict__ Xlo,
     unsigned short* __restrict__ WThi,
     float* __restrict__ logits)
{
    __shared__ float tile[64][65];
    const int bid = blockIdx.x;
    const int t = threadIdx.x;

    if (bid < 4096) {
        // split hidden f32 -> (hi, lo) bf16, same layout; 4 coalesced float4 per thread
#pragma unroll
        for (int j = 0; j < 4; ++j) {
            int i = bid * 1024 + j * 256 + t;
            float4 x = ((const float4*)hidden)[i];
            ushort4 h, l;
            h.x = f2bf_rne(x.x); l.x = f2bf_rne(x.x - b2f(h.x));
            h.y = f2bf_rne(x.y); l.y = f2bf_rne(x.y - b2f(h.y));
            h.z = f2bf_rne(x.z); l.z = f2bf_rne(x.z - b2f(h.z));
            h.w = f2bf_rne(x.w); l.w = f2bf_rne(x.w - b2f(h.w));
            ((ushort4*)Xhi)[i] = h;
            ((ushort4*)Xlo)[i] = l;
        }
    } else if (bid < 6144) {
        // transpose W [D][H] -> WT [H][D] for both matrices, bf16 hi only
        int wb  = bid - 4096;
        int z   = wb >> 10;                   // 0=boundary, 1=reset
        int rem = wb & 1023;
        int bx  = (rem & 63) * 64;            // H direction
        int by  = (rem >> 6) * 64;            // D direction
        const float* src = z ? Wr1 : Wb1;
        const size_t moff = (size_t)z * H_DIM * D_IN;
        const int c4 = (t & 15) * 4;
        const int r0 = (t >> 4) * 4;
#pragma unroll
        for (int rr = 0; rr < 4; ++rr) {
            int r = r0 + rr;
            float4 v = *(const float4*)(src + (size_t)(by + r) * H_DIM + bx + c4);
            tile[r][c4 + 0] = v.x; tile[r][c4 + 1] = v.y;
            tile[r][c4 + 2] = v.z; tile[r][c4 + 3] = v.w;
        }
        __syncthreads();
#pragma unroll
        for (int rr = 0; rr < 4; ++rr) {
            int c = r0 + rr;
            ushort4 h;
            h.x = f2bf_rne(tile[c4 + 0][c]);
            h.y = f2bf_rne(tile[c4 + 1][c]);
            h.z = f2bf_rne(tile[c4 + 2][c]);
            h.w = f2bf_rne(tile[c4 + 3][c]);
            size_t o = moff + (size_t)(bx + c) * D_IN + by + c4;
            *(ushort4*)(WThi + o) = h;
        }
    } else {
#pragma unroll
        for (int j = 0; j < 4; ++j)
            logits[(bid - 6144) * 1024 + j * 256 + t] = 0.f;   // 32 blocks x 1024 = 32768
    }
}

// ------------- fused split-f32 GEMM + relu + (.)@W2 reduction, 2 products, 2-PANEL PHASES -------------
// Stall model from r0/r9 (single-buf) vs r1/r5/r8 (dbuf): stall ~= 6.5-7.4us PER BARRIER
// PHASE, independent of MFMA/phase; dbuf is counterproductive at HIP level (compiler
// serializes ds_read vs in-flight global_load_lds). Lever: FEWER, FATTER phases.
// This round: BK=64 per barrier as TWO independent 32-wide panels, each a VERBATIM copy
// of r9's proven layout (64B rows, XOR swizzle phys16Bchunk = logical ^ ((row>>1)&3),
// staging dest = linear t*16B). 16 phases instead of 32; 128 MFMA/wave/phase.
// LDS 2 x (8+8+16) KB = 64 KB -> still 2 blocks/CU. K-order per accumulator identical to
// r9 (hi(c),lo(c) in chunk order) -> bit-identical FP chains, absmax must stay 0.0078125.
__global__ void __launch_bounds__(256, 2)
gemm_fused2(const unsigned short* __restrict__ Xhi, const unsigned short* __restrict__ Xlo,
            const unsigned short* __restrict__ WThi,
            const float* __restrict__ b1b, const float* __restrict__ b1r,
            const float* __restrict__ w2b, const float* __restrict__ w2r,
            float* __restrict__ logits)              // [2][B][T] f32, atomically accumulated
{
    __shared__ __align__(16) unsigned short Ahi_s[2][128 * 32];   // 2 x 8 KB
    __shared__ __align__(16) unsigned short Alo_s[2][128 * 32];   // 2 x 8 KB
    __shared__ __align__(16) unsigned short Bhi_s[2][256 * 32];   // 2 x 16 KB

    const int t    = threadIdx.x;
    const int wave = t >> 6;
    const int lane = t & 63;
    const int quad = lane >> 4;
    const int lr   = lane & 15;
    const int w_m  = (wave & 1) * 64;
    const int w_n  = (wave >> 1) * 128;

    const int mat = blockIdx.z;
    const int n0  = blockIdx.x * 256;
    const int m0  = blockIdx.y * 128;

    const size_t aoff = (size_t)m0 * D_IN;
    const size_t boff = (size_t)mat * H_DIM * D_IN + (size_t)n0 * D_IN;
    const unsigned short* Ah = Xhi + aoff;
    const unsigned short* Al = Xlo + aoff;
    const unsigned short* Bh = WThi + boff;
    const float* b1 = mat ? b1r : b1b;
    const float* w2 = mat ? w2r : w2b;
    float* out = logits + mat * M_ROWS;

    // staging (per 32-wide panel, r9 verbatim): thread t fills phys chunk (t&3) of
    // row (t>>2)+i*64. Source global chunk = (t&3) ^ ((row>>1)&3) = (t&3) ^ ((t>>3)&3).
    const int srow = t >> 2;
    const int scol = (((t & 3) ^ ((t >> 3) & 3)) * 8);

    // fragment read offsets (loop-invariant); r9 proven conflict-free swizzle
    int afo[4], bfo[8];
#pragma unroll
    for (int i = 0; i < 4; ++i) {
        int row = w_m + i * 16 + lr;
        afo[i] = row * 32 + ((quad ^ ((row >> 1) & 3)) * 8);
    }
#pragma unroll
    for (int j = 0; j < 8; ++j) {
        int row = w_n + j * 16 + lr;
        bfo[j] = row * 32 + ((quad ^ ((row >> 1) & 3)) * 8);
    }

    f32x4 acc[4][8] = {};

#pragma unroll 1
    for (int kt = 0; kt < D_IN / 64; ++kt) {
        // stage BOTH panels (k0 and k0+32), then ONE barrier
#pragma unroll
        for (int p = 0; p < 2; ++p) {
            const int k0 = kt * 64 + p * 32;
#pragma unroll
            for (int i = 0; i < 2; ++i)
                load_lds16(Ah + (size_t)(i * 64 + srow) * D_IN + k0 + scol,
                           &Ahi_s[p][0] + i * 2048 + wave * 512);
#pragma unroll
            for (int i = 0; i < 2; ++i)
                load_lds16(Al + (size_t)(i * 64 + srow) * D_IN + k0 + scol,
                           &Alo_s[p][0] + i * 2048 + wave * 512);
#pragma unroll
            for (int i = 0; i < 4; ++i)
                load_lds16(Bh + (size_t)(i * 64 + srow) * D_IN + k0 + scol,
                           &Bhi_s[p][0] + i * 2048 + wave * 512);
        }
        __syncthreads();

        // compute panel 0 then panel 1; within each: hi-set then lo-set (r9's k-order)
#pragma unroll
        for (int p = 0; p < 2; ++p) {
            bf16x8 afh[4], afl[4], bfh[8];
#pragma unroll
            for (int i = 0; i < 4; ++i) {
                afh[i] = *(const bf16x8*)(&Ahi_s[p][0] + afo[i]);
                afl[i] = *(const bf16x8*)(&Alo_s[p][0] + afo[i]);
            }
#pragma unroll
            for (int j = 0; j < 8; ++j)
                bfh[j] = *(const bf16x8*)(&Bhi_s[p][0] + bfo[j]);
#pragma unroll
            for (int i = 0; i < 4; ++i)
#pragma unroll
                for (int j = 0; j < 8; ++j)
                    acc[i][j] = __builtin_amdgcn_mfma_f32_16x16x32_bf16(afh[i], bfh[j], acc[i][j], 0, 0, 0);
#pragma unroll
            for (int i = 0; i < 4; ++i)
#pragma unroll
                for (int j = 0; j < 8; ++j)
                    acc[i][j] = __builtin_amdgcn_mfma_f32_16x16x32_bf16(afl[i], bfh[j], acc[i][j], 0, 0, 0);
        }
        __syncthreads();
    }

    // epilogue: relu(C + b1)*w2, reduce over this tile's n, accumulate to logits
    float b1v[8], w2v[8];
#pragma unroll
    for (int j = 0; j < 8; ++j) {
        int n = n0 + w_n + j * 16 + lr;              // C/D col = lane&15
        b1v[j] = b1[n];
        w2v[j] = w2[n];
    }
#pragma unroll
    for (int i = 0; i < 4; ++i) {
#pragma unroll
        for (int r = 0; r < 4; ++r) {
            float s = 0.f;
#pragma unroll
            for (int j = 0; j < 8; ++j) {
                float h = acc[i][j][r] + b1v[j];
                s += fmaxf(h, 0.f) * w2v[j];
            }
            s += __shfl_xor(s, 1, 64);
            s += __shfl_xor(s, 2, 64);
            s += __shfl_xor(s, 4, 64);
            s += __shfl_xor(s, 8, 64);
            if (lr == 0) {
                int m = m0 + w_m + i * 16 + quad * 4 + r;   // C/D row = quad*4 + reg
                atomicAdd(&out[(m & (BATCH - 1)) * T_STEPS + (m >> 2)], s);  // -> [b][t]
            }
        }
    }
}

// ------------- finish: soft output (blocks 0..63) + serial LIF scan (block 64) -------------
// Scan is a 4096-step serial chain; loads are L2-latency-bound if issued in-chain.
// Fix: 16-step register prefetch ring (load chunk c+1 before processing chunk c;
// ~250 cyc of chain work hides the ~200 cyc L2 latency). x+bb2 / rl>0 computed off-chain.
__global__ void __launch_bounds__(256)
finish(const float* __restrict__ logits,
       const float* __restrict__ bb2p, const float* __restrict__ br2p,
       float* __restrict__ out)
{
    if (blockIdx.x < 64) {
        int i = blockIdx.x * 256 + threadIdx.x;
        out[i] = logits[i] + bb2p[0];                // soft = boundary logits [b][t] + bb2
        return;
    }
    int b = threadIdx.x;
    if (b >= BATCH) return;
    const float bb2 = bb2p[0];
    const float br2 = br2p[0];
    const float* xb = logits + b * T_STEPS;          // boundary logits, [b][t]
    const float* xr = logits + M_ROWS + b * T_STEPS; // reset logits
    float* hb = out + M_ROWS + b * T_STEPS;

    float4 cx[4], cr[4], nx[4] = {}, nr[4] = {};
#pragma unroll
    for (int q = 0; q < 4; ++q) {
        cx[q] = *(const float4*)(xb + q * 4);
        cr[q] = *(const float4*)(xr + q * 4);
    }

    float v = 0.f;
    for (int t0 = 0; t0 < T_STEPS; t0 += 16) {
        if (t0 + 16 < T_STEPS) {
#pragma unroll
            for (int q = 0; q < 4; ++q) {
                nx[q] = *(const float4*)(xb + t0 + 16 + q * 4);
                nr[q] = *(const float4*)(xr + t0 + 16 + q * 4);
            }
        }
#pragma unroll
        for (int q = 0; q < 4; ++q) {
            // off-chain precompute (same ops as before, just hoisted)
            float xs[4] = { cx[q].x + bb2, cx[q].y + bb2, cx[q].z + bb2, cx[q].w + bb2 };
            bool  rm[4] = { cr[q].x + br2 > 0.f, cr[q].y + br2 > 0.f,
                            cr[q].z + br2 > 0.f, cr[q].w + br2 > 0.f };
            float4 sv;
#pragma unroll
            for (int u = 0; u < 4; ++u) {
                v = v + (xs[u] - v) * 0.5f;          // bit-identical to reference step
                bool spike = (v >= 1.0f);
                ((float*)&sv)[u] = spike ? 1.0f : 0.0f;
                v = (spike || rm[u]) ? 0.f : v;
            }
            *(float4*)(hb + t0 + q * 4) = sv;
        }
#pragma unroll
        for (int q = 0; q < 4; ++q) { cx[q] = nx[q]; cr[q] = nr[q]; }
    }
}

extern "C" void kernel_launch(void* const* d_in, const int* in_sizes, int n_in,
                              void* d_out, int out_size, void* d_ws, size_t ws_size,
                              hipStream_t stream) {
    // dict order (confirmed): hidden, Wb1, bb1, Wb2, bb2, Wr1, br1, Wr2, br2
    const float* hidden = (const float*)d_in[0];   // [T,B,D] f32
    const float* Wb1    = (const float*)d_in[1];   // [D,H]
    const float* bb1    = (const float*)d_in[2];   // [H]
    const float* Wb2    = (const float*)d_in[3];   // [H,1]
    const float* bb2    = (const float*)d_in[4];   // [1]
    const float* Wr1    = (const float*)d_in[5];
    const float* br1    = (const float*)d_in[6];
    const float* Wr2    = (const float*)d_in[7];
    const float* br2    = (const float*)d_in[8];
    float* out = (float*)d_out;                    // f32: [soft B*T][hard B*T]

    // ws layout (unchanged, 96.13 MB): Xhi 32MB | Xlo 32MB | WThi 16MB | (WTlo unused) | logits
    unsigned short* Xhi  = (unsigned short*)d_ws;
    unsigned short* Xlo  = Xhi  + (size_t)M_ROWS * D_IN;
    unsigned short* WThi = Xlo  + (size_t)M_ROWS * D_IN;
    unsigned short* WTlo = WThi + (size_t)2 * H_DIM * D_IN;   // region kept for layout stability
    float* logits = (float*)(WTlo + (size_t)2 * H_DIM * D_IN);

    prep<<<dim3(6176), 256, 0, stream>>>(hidden, Wb1, Wr1, Xhi, Xlo, WThi, logits);
    gemm_fused2<<<dim3(H_DIM / 256, M_ROWS / 128, 2), 256, 0, stream>>>(
        Xhi, Xlo, WThi, bb1, br1, Wb2, Wr2, logits);
    finish<<<dim3(65), 256, 0, stream>>>(logits, bb2, br2, out);
}

// Round 11
// 605.993 us; speedup vs baseline: 1.2314x; 1.2314x over previous
//
#include <hip/hip_runtime.h>
#include <hip/hip_bf16.h>
#include <stdint.h>

// Problem constants: [T,B,D]=[4096,4,1024], H=4096. f32 inputs, f32 outputs.
// Outputs: soft [B,T] f32 at out[0..16384), hard [B,T] f32 at out[16384..32768).
#define T_STEPS 4096
#define BATCH   4
#define D_IN    1024
#define H_DIM   4096
#define M_ROWS  (T_STEPS * BATCH)

typedef __attribute__((ext_vector_type(8))) _Float16 f16x8;
typedef __attribute__((ext_vector_type(4))) float    f32x4;

__device__ __forceinline__ unsigned short f2h(float f) {
    union { _Float16 h; unsigned short u; } v;
    v.h = (_Float16)f;                      // RNE by default
    return v.u;
}

__device__ __forceinline__ void load_lds16(const unsigned short* g, unsigned short* l) {
    __builtin_amdgcn_global_load_lds(
        (const __attribute__((address_space(1))) void*)g,
        (__attribute__((address_space(3))) void*)l, 16, 0, 0);
}

// ---------------- prep: X f32->f16 (fat blocks) + transpose W f32->f16 + zero logits ----------------
// f16 (10 mantissa bits) single-product replaces the bf16 hi/lo split entirely:
// per-element rel err 2^-11 -> predicted logit error ~3x SMALLER than the passing
// bf16-2-product version. No Xlo/WTlo: prep writes half the bytes of the split version.
// blocks [0,4096): cvt_x (4 float4/thread) | [4096,6144): W transpose | [6144,6176): zero
__global__ void __launch_bounds__(256)
prep(const float* __restrict__ hidden,
     const float* __restrict__ Wb1, const float* __restrict__ Wr1,
     unsigned short* __restrict__ Xh, unsigned short* __restrict__ WTh,
     float* __restrict__ logits)
{
    __shared__ float tile[64][65];
    const int bid = blockIdx.x;
    const int t = threadIdx.x;

    if (bid < 4096) {
#pragma unroll
        for (int j = 0; j < 4; ++j) {
            int i = bid * 1024 + j * 256 + t;
            float4 x = ((const float4*)hidden)[i];
            ushort4 h;
            h.x = f2h(x.x); h.y = f2h(x.y); h.z = f2h(x.z); h.w = f2h(x.w);
            ((ushort4*)Xh)[i] = h;
        }
    } else if (bid < 6144) {
        // transpose W [D][H] -> WT [H][D] for both matrices, f16
        int wb  = bid - 4096;
        int z   = wb >> 10;                   // 0=boundary, 1=reset
        int rem = wb & 1023;
        int bx  = (rem & 63) * 64;            // H direction
        int by  = (rem >> 6) * 64;            // D direction
        const float* src = z ? Wr1 : Wb1;
        const size_t moff = (size_t)z * H_DIM * D_IN;
        const int c4 = (t & 15) * 4;
        const int r0 = (t >> 4) * 4;
#pragma unroll
        for (int rr = 0; rr < 4; ++rr) {
            int r = r0 + rr;
            float4 v = *(const float4*)(src + (size_t)(by + r) * H_DIM + bx + c4);
            tile[r][c4 + 0] = v.x; tile[r][c4 + 1] = v.y;
            tile[r][c4 + 2] = v.z; tile[r][c4 + 3] = v.w;
        }
        __syncthreads();
#pragma unroll
        for (int rr = 0; rr < 4; ++rr) {
            int c = r0 + rr;
            ushort4 h;
            h.x = f2h(tile[c4 + 0][c]);
            h.y = f2h(tile[c4 + 1][c]);
            h.z = f2h(tile[c4 + 2][c]);
            h.w = f2h(tile[c4 + 3][c]);
            size_t o = moff + (size_t)(bx + c) * D_IN + by + c4;
            *(ushort4*)(WTh + o) = h;
        }
    } else {
#pragma unroll
        for (int j = 0; j < 4; ++j)
            logits[(bid - 6144) * 1024 + j * 256 + t] = 0.f;   // 32 blocks x 1024 = 32768
    }
}

// ------------- fused f16 GEMM + relu + (.)@W2 reduction, single product -------------
// Structure = r10 VERBATIM minus the lo-product (proven: 2 blocks/CU, two 32-wide panels
// per barrier, 64B rows, 0-conflict XOR swizzle phys16Bchunk = logical ^ ((row>>1)&3),
// staging dest = linear t*16B, 16x16x32 MFMA shape family). Per phase: 12 staging
// loads/thread, 64 MFMA/wave (2 panels x 4x8 frags x 1 product). LDS 48 KB.
// Evidence r8/r9/r10: family is staging-throughput-limited (~40-53 us per staged GB,
// scheduling-invariant) -> f16 wins on BOTH axes: MFMA floor 265->132 us, staged 4->3.1 GB.
__global__ void __launch_bounds__(256, 2)
gemm_f16(const unsigned short* __restrict__ Xh, const unsigned short* __restrict__ WTh,
         const float* __restrict__ b1b, const float* __restrict__ b1r,
         const float* __restrict__ w2b, const float* __restrict__ w2r,
         float* __restrict__ logits)              // [2][B][T] f32, atomically accumulated
{
    __shared__ __align__(16) unsigned short Ah_s[2][128 * 32];   // 2 x 8 KB
    __shared__ __align__(16) unsigned short Bh_s[2][256 * 32];   // 2 x 16 KB

    const int t    = threadIdx.x;
    const int wave = t >> 6;
    const int lane = t & 63;
    const int quad = lane >> 4;
    const int lr   = lane & 15;
    const int w_m  = (wave & 1) * 64;
    const int w_n  = (wave >> 1) * 128;

    const int mat = blockIdx.z;
    const int n0  = blockIdx.x * 256;
    const int m0  = blockIdx.y * 128;

    const size_t aoff = (size_t)m0 * D_IN;
    const size_t boff = (size_t)mat * H_DIM * D_IN + (size_t)n0 * D_IN;
    const unsigned short* Ah = Xh + aoff;
    const unsigned short* Bh = WTh + boff;
    const float* b1 = mat ? b1r : b1b;
    const float* w2 = mat ? w2r : w2b;
    float* out = logits + mat * M_ROWS;

    // staging (per 32-wide panel, r9/r10 verbatim): thread t fills phys chunk (t&3) of
    // row (t>>2)+i*64. Source global chunk = (t&3) ^ ((row>>1)&3) = (t&3) ^ ((t>>3)&3).
    const int srow = t >> 2;
    const int scol = (((t & 3) ^ ((t >> 3) & 3)) * 8);

    // fragment read offsets (loop-invariant); proven conflict-free swizzle
    int afo[4], bfo[8];
#pragma unroll
    for (int i = 0; i < 4; ++i) {
        int row = w_m + i * 16 + lr;
        afo[i] = row * 32 + ((quad ^ ((row >> 1) & 3)) * 8);
    }
#pragma unroll
    for (int j = 0; j < 8; ++j) {
        int row = w_n + j * 16 + lr;
        bfo[j] = row * 32 + ((quad ^ ((row >> 1) & 3)) * 8);
    }

    f32x4 acc[4][8] = {};

#pragma unroll 1
    for (int kt = 0; kt < D_IN / 64; ++kt) {
        // stage BOTH panels (k0 and k0+32), then ONE barrier
#pragma unroll
        for (int p = 0; p < 2; ++p) {
            const int k0 = kt * 64 + p * 32;
#pragma unroll
            for (int i = 0; i < 2; ++i)
                load_lds16(Ah + (size_t)(i * 64 + srow) * D_IN + k0 + scol,
                           &Ah_s[p][0] + i * 2048 + wave * 512);
#pragma unroll
            for (int i = 0; i < 4; ++i)
                load_lds16(Bh + (size_t)(i * 64 + srow) * D_IN + k0 + scol,
                           &Bh_s[p][0] + i * 2048 + wave * 512);
        }
        __syncthreads();

#pragma unroll
        for (int p = 0; p < 2; ++p) {
            f16x8 af[4], bf[8];
#pragma unroll
            for (int i = 0; i < 4; ++i)
                af[i] = *(const f16x8*)(&Ah_s[p][0] + afo[i]);
#pragma unroll
            for (int j = 0; j < 8; ++j)
                bf[j] = *(const f16x8*)(&Bh_s[p][0] + bfo[j]);
#pragma unroll
            for (int i = 0; i < 4; ++i)
#pragma unroll
                for (int j = 0; j < 8; ++j)
                    acc[i][j] = __builtin_amdgcn_mfma_f32_16x16x32_f16(af[i], bf[j], acc[i][j], 0, 0, 0);
        }
        __syncthreads();
    }

    // epilogue: relu(C + b1)*w2, reduce over this tile's n, accumulate to logits
    float b1v[8], w2v[8];
#pragma unroll
    for (int j = 0; j < 8; ++j) {
        int n = n0 + w_n + j * 16 + lr;              // C/D col = lane&15
        b1v[j] = b1[n];
        w2v[j] = w2[n];
    }
#pragma unroll
    for (int i = 0; i < 4; ++i) {
#pragma unroll
        for (int r = 0; r < 4; ++r) {
            float s = 0.f;
#pragma unroll
            for (int j = 0; j < 8; ++j) {
                float h = acc[i][j][r] + b1v[j];
                s += fmaxf(h, 0.f) * w2v[j];
            }
            s += __shfl_xor(s, 1, 64);
            s += __shfl_xor(s, 2, 64);
            s += __shfl_xor(s, 4, 64);
            s += __shfl_xor(s, 8, 64);
            if (lr == 0) {
                int m = m0 + w_m + i * 16 + quad * 4 + r;   // C/D row = quad*4 + reg
                atomicAdd(&out[(m & (BATCH - 1)) * T_STEPS + (m >> 2)], s);  // -> [b][t]
            }
        }
    }
}

// ------------- finish: soft output (blocks 0..63) + serial LIF scan (block 64) -------------
// Scan is a 4096-step serial chain; loads are L2-latency-bound if issued in-chain.
// Fix: 16-step register prefetch ring (load chunk c+1 before processing chunk c;
// ~250 cyc of chain work hides the ~200 cyc L2 latency). x+bb2 / rl>0 computed off-chain.
__global__ void __launch_bounds__(256)
finish(const float* __restrict__ logits,
       const float* __restrict__ bb2p, const float* __restrict__ br2p,
       float* __restrict__ out)
{
    if (blockIdx.x < 64) {
        int i = blockIdx.x * 256 + threadIdx.x;
        out[i] = logits[i] + bb2p[0];                // soft = boundary logits [b][t] + bb2
        return;
    }
    int b = threadIdx.x;
    if (b >= BATCH) return;
    const float bb2 = bb2p[0];
    const float br2 = br2p[0];
    const float* xb = logits + b * T_STEPS;          // boundary logits, [b][t]
    const float* xr = logits + M_ROWS + b * T_STEPS; // reset logits
    float* hb = out + M_ROWS + b * T_STEPS;

    float4 cx[4], cr[4], nx[4] = {}, nr[4] = {};
#pragma unroll
    for (int q = 0; q < 4; ++q) {
        cx[q] = *(const float4*)(xb + q * 4);
        cr[q] = *(const float4*)(xr + q * 4);
    }

    float v = 0.f;
    for (int t0 = 0; t0 < T_STEPS; t0 += 16) {
        if (t0 + 16 < T_STEPS) {
#pragma unroll
            for (int q = 0; q < 4; ++q) {
                nx[q] = *(const float4*)(xb + t0 + 16 + q * 4);
                nr[q] = *(const float4*)(xr + t0 + 16 + q * 4);
            }
        }
#pragma unroll
        for (int q = 0; q < 4; ++q) {
            // off-chain precompute (same ops as before, just hoisted)
            float xs[4] = { cx[q].x + bb2, cx[q].y + bb2, cx[q].z + bb2, cx[q].w + bb2 };
            bool  rm[4] = { cr[q].x + br2 > 0.f, cr[q].y + br2 > 0.f,
                            cr[q].z + br2 > 0.f, cr[q].w + br2 > 0.f };
            float4 sv;
#pragma unroll
            for (int u = 0; u < 4; ++u) {
                v = v + (xs[u] - v) * 0.5f;          // bit-identical to reference step
                bool spike = (v >= 1.0f);
                ((float*)&sv)[u] = spike ? 1.0f : 0.0f;
                v = (spike || rm[u]) ? 0.f : v;
            }
            *(float4*)(hb + t0 + q * 4) = sv;
        }
#pragma unroll
        for (int q = 0; q < 4; ++q) { cx[q] = nx[q]; cr[q] = nr[q]; }
    }
}

extern "C" void kernel_launch(void* const* d_in, const int* in_sizes, int n_in,
                              void* d_out, int out_size, void* d_ws, size_t ws_size,
                              hipStream_t stream) {
    // dict order (confirmed): hidden, Wb1, bb1, Wb2, bb2, Wr1, br1, Wr2, br2
    const float* hidden = (const float*)d_in[0];   // [T,B,D] f32
    const float* Wb1    = (const float*)d_in[1];   // [D,H]
    const float* bb1    = (const float*)d_in[2];   // [H]
    const float* Wb2    = (const float*)d_in[3];   // [H,1]
    const float* bb2    = (const float*)d_in[4];   // [1]
    const float* Wr1    = (const float*)d_in[5];
    const float* br1    = (const float*)d_in[6];
    const float* Wr2    = (const float*)d_in[7];
    const float* br2    = (const float*)d_in[8];
    float* out = (float*)d_out;                    // f32: [soft B*T][hard B*T]

    // ws layout: Xh 32MB | WTh 16MB | logits 128KB  (well under the 96 MB workspace)
    unsigned short* Xh  = (unsigned short*)d_ws;
    unsigned short* WTh = Xh + (size_t)M_ROWS * D_IN;
    float* logits = (float*)(WTh + (size_t)2 * H_DIM * D_IN);

    prep<<<dim3(6176), 256, 0, stream>>>(hidden, Wb1, Wr1, Xh, WTh, logits);
    gemm_f16<<<dim3(H_DIM / 256, M_ROWS / 128, 2), 256, 0, stream>>>(
        Xh, WTh, bb1, br1, Wb2, Wr2, logits);
    finish<<<dim3(65), 256, 0, stream>>>(logits, bb2, br2, out);
}